// Round 1
// baseline (202.574 us; speedup 1.0000x reference)
//
#include <hip/hip_runtime.h>
#include <math.h>

// Problem shape (fixed by reference setup_inputs):
//   feature_map: (B=8, D=256, H=128, W=128) fp32
//   para_code:   (8, 256)
//   W1 (256,256) b1(256) | Ws (256,256) bs(256) | Wr (256,256) br(256)
//   Wt (256,512) bt(512)
// Output: (8, 256, 128, 128) fp32

#define B_  8
#define D_  256
#define H_  128
#define W_  128
#define PC_ 256     // para/feature channels
#define PI_F 3.14159f

// ---------------- Kernel 1: p = relu(para_code @ W1 + b1) -------------------
// grid = B_, block = 256. para row staged in LDS; W1 column access coalesced
// across threads (thread j reads W1[k*256 + j]).
__global__ void k_mlp_p(const float* __restrict__ para,
                        const float* __restrict__ W1,
                        const float* __restrict__ b1,
                        float* __restrict__ p_out) {
    __shared__ float sp[PC_];
    const int b = blockIdx.x;
    const int j = threadIdx.x;
    sp[j] = para[b * PC_ + j];
    __syncthreads();
    float acc = b1[j];
#pragma unroll 8
    for (int k = 0; k < PC_; ++k) {
        acc = fmaf(sp[k], W1[k * PC_ + j], acc);
    }
    p_out[b * PC_ + j] = fmaxf(acc, 0.0f);
}

// ---------------- Kernel 2: heads -> per-(b,d) params -----------------------
// grid = B_, block = 256 (one thread per d). All four heads fused in one
// K-loop so p is read once from LDS. Outputs SoA arrays of length B_*D_.
__global__ void k_heads(const float* __restrict__ p,
                        const float* __restrict__ Ws, const float* __restrict__ bs,
                        const float* __restrict__ Wr, const float* __restrict__ br,
                        const float* __restrict__ Wt, const float* __restrict__ bt,
                        float* __restrict__ sc_o, float* __restrict__ c_o,
                        float* __restrict__ s_o,  float* __restrict__ tx_o,
                        float* __restrict__ ty_o) {
    __shared__ float sp[PC_];
    const int b = blockIdx.x;
    const int d = threadIdx.x;
    sp[d] = p[b * PC_ + d];
    __syncthreads();

    float as = bs[d];
    float ar = br[d];
    float t0 = bt[2 * d];
    float t1 = bt[2 * d + 1];
#pragma unroll 4
    for (int k = 0; k < PC_; ++k) {
        const float pk = sp[k];
        as = fmaf(pk, Ws[k * PC_ + d], as);
        ar = fmaf(pk, Wr[k * PC_ + d], ar);
        t0 = fmaf(pk, Wt[k * (2 * PC_) + 2 * d],     t0);
        t1 = fmaf(pk, Wt[k * (2 * PC_) + 2 * d + 1], t1);
    }
    const int o = b * D_ + d;
    const float scale = 2.0f / (1.0f + expf(-as));      // sigmoid * 2
    const float ang   = tanhf(ar) * PI_F;
    sc_o[o] = scale;
    c_o[o]  = cosf(ang);
    s_o[o]  = sinf(ang);
    tx_o[o] = tanhf(t0);
    ty_o[o] = tanhf(t1);
}

// ---------------- Kernel 3: affine grid-sample (bilinear, border) -----------
// One block per (b,d) plane (2048 blocks, 256 threads). Each block's 64 KiB
// plane stays hot in L1/L2 across the bilinear re-touches.
__global__ void k_sample(const float* __restrict__ fm,
                         const float* __restrict__ sc_a, const float* __restrict__ c_a,
                         const float* __restrict__ s_a,  const float* __restrict__ tx_a,
                         const float* __restrict__ ty_a,
                         float* __restrict__ out) {
    const int plane = blockIdx.x;                 // 0 .. B_*D_-1
    const float* __restrict__ img = fm + (size_t)plane * (H_ * W_);
    float* __restrict__ op = out + (size_t)plane * (H_ * W_);

    const float sc = sc_a[plane];
    const float cc = c_a[plane];
    const float ss = s_a[plane];
    const float tx = tx_a[plane];
    const float ty = ty_a[plane];

    // Fold the normalized->pixel mapping into affine coefficients:
    //   gx = w*gstep - 1, gy = h*gstep - 1, gstep = 2/(W-1)
    //   nx = (cc*gx - ss*gy)*sc + tx ;  x = (nx+1)*64 - 0.5   (align_corners=False)
    const float gstep = 2.0f / (float)(W_ - 1);

    for (int i = threadIdx.x; i < H_ * W_; i += blockDim.x) {
        const int h = i >> 7;          // W_ = 128
        const int w = i & (W_ - 1);
        const float gx = (float)w * gstep - 1.0f;
        const float gy = (float)h * gstep - 1.0f;
        const float nx = (cc * gx - ss * gy) * sc + tx;
        const float ny = (ss * gx + cc * gy) * sc + ty;

        float x = (nx + 1.0f) * ((float)W_ * 0.5f) - 0.5f;
        float y = (ny + 1.0f) * ((float)H_ * 0.5f) - 0.5f;
        x = fminf(fmaxf(x, 0.0f), (float)(W_ - 1));   // border padding
        y = fminf(fmaxf(y, 0.0f), (float)(H_ - 1));

        const float x0f = floorf(x);
        const float y0f = floorf(y);
        const float wx = x - x0f;
        const float wy = y - y0f;
        const int x0 = (int)x0f;
        const int y0 = (int)y0f;
        const int x1 = min(x0 + 1, W_ - 1);
        const int y1 = min(y0 + 1, H_ - 1);

        const float* r0 = img + y0 * W_;
        const float* r1 = img + y1 * W_;
        const float v00 = r0[x0];
        const float v01 = r0[x1];
        const float v10 = r1[x0];
        const float v11 = r1[x1];

        const float top = v00 + wx * (v01 - v00);
        const float bot = v10 + wx * (v11 - v10);
        op[i] = top + wy * (bot - top);
    }
}

extern "C" void kernel_launch(void* const* d_in, const int* in_sizes, int n_in,
                              void* d_out, int out_size, void* d_ws, size_t ws_size,
                              hipStream_t stream) {
    const float* feature_map = (const float*)d_in[0];
    const float* para_code   = (const float*)d_in[1];
    const float* W1 = (const float*)d_in[2];
    const float* b1 = (const float*)d_in[3];
    const float* Ws = (const float*)d_in[4];
    const float* bs = (const float*)d_in[5];
    const float* Wr = (const float*)d_in[6];
    const float* br = (const float*)d_in[7];
    const float* Wt = (const float*)d_in[8];
    const float* bt = (const float*)d_in[9];
    float* out = (float*)d_out;

    // Workspace layout (floats): p[B_*PC_] | sc | c | s | tx | ty  (each B_*D_)
    float* ws_f = (float*)d_ws;
    float* p_buf = ws_f;                       // 2048
    float* sc_a  = p_buf + B_ * PC_;           // 2048
    float* c_a   = sc_a + B_ * D_;
    float* s_a   = c_a  + B_ * D_;
    float* tx_a  = s_a  + B_ * D_;
    float* ty_a  = tx_a + B_ * D_;

    k_mlp_p<<<B_, PC_, 0, stream>>>(para_code, W1, b1, p_buf);
    k_heads<<<B_, D_, 0, stream>>>(p_buf, Ws, bs, Wr, br, Wt, bt,
                                   sc_a, c_a, s_a, tx_a, ty_a);
    k_sample<<<B_ * D_, 256, 0, stream>>>(feature_map, sc_a, c_a, s_a, tx_a, ty_a, out);
}

// Round 2
// 116.934 us; speedup vs baseline: 1.7324x; 1.7324x over previous
//
#include <hip/hip_runtime.h>
#include <math.h>

// Problem shape (fixed by reference setup_inputs):
//   feature_map: (B=8, D=256, H=128, W=128) fp32
//   para_code:   (8, 256)
//   W1 (256,256) b1(256) | Ws (256,256) bs(256) | Wr (256,256) br(256)
//   Wt (256,512) bt(512)
// Output: (8, 256, 128, 128) fp32

#define B_  8
#define D_  256
#define H_  128
#define W_  128
#define PC_ 256
#define PI_F 3.14159f

// ---------------- Kernel 1: p = relu(para_code @ W1 + b1) -------------------
__global__ void k_mlp_p(const float* __restrict__ para,
                        const float* __restrict__ W1,
                        const float* __restrict__ b1,
                        float* __restrict__ p_out) {
    __shared__ float sp[PC_];
    const int b = blockIdx.x;
    const int j = threadIdx.x;
    sp[j] = para[b * PC_ + j];
    __syncthreads();
    float acc = b1[j];
#pragma unroll 8
    for (int k = 0; k < PC_; ++k) {
        acc = fmaf(sp[k], W1[k * PC_ + j], acc);
    }
    p_out[b * PC_ + j] = fmaxf(acc, 0.0f);
}

// ---------------- Kernel 2: heads -> per-(b,d) params -----------------------
__global__ void k_heads(const float* __restrict__ p,
                        const float* __restrict__ Ws, const float* __restrict__ bs,
                        const float* __restrict__ Wr, const float* __restrict__ br,
                        const float* __restrict__ Wt, const float* __restrict__ bt,
                        float* __restrict__ sc_o, float* __restrict__ c_o,
                        float* __restrict__ s_o,  float* __restrict__ tx_o,
                        float* __restrict__ ty_o) {
    __shared__ float sp[PC_];
    const int b = blockIdx.x;
    const int d = threadIdx.x;
    sp[d] = p[b * PC_ + d];
    __syncthreads();

    float as = bs[d];
    float ar = br[d];
    float t0 = bt[2 * d];
    float t1 = bt[2 * d + 1];
#pragma unroll 4
    for (int k = 0; k < PC_; ++k) {
        const float pk = sp[k];
        as = fmaf(pk, Ws[k * PC_ + d], as);
        ar = fmaf(pk, Wr[k * PC_ + d], ar);
        t0 = fmaf(pk, Wt[k * (2 * PC_) + 2 * d],     t0);
        t1 = fmaf(pk, Wt[k * (2 * PC_) + 2 * d + 1], t1);
    }
    const int o = b * D_ + d;
    const float scale = 2.0f / (1.0f + expf(-as));      // sigmoid * 2
    const float ang   = tanhf(ar) * PI_F;
    sc_o[o] = scale;
    c_o[o]  = cosf(ang);
    s_o[o]  = sinf(ang);
    tx_o[o] = tanhf(t0);
    ty_o[o] = tanhf(t1);
}

// ---------------- Kernel 3: affine grid-sample via LDS-staged plane ---------
// One block (512 threads) per (b,d) plane. The whole 64 KiB plane is staged
// into LDS with coalesced float4 loads (1x HBM read), then every bilinear
// gather is an LDS read — no L2 thrash (previous version: 16 MiB active
// working set per XCD vs 4 MiB L2 -> L3-latency-bound at 17% VALUBusy).
__global__ __launch_bounds__(512)
void k_sample(const float* __restrict__ fm,
              const float* __restrict__ sc_a, const float* __restrict__ c_a,
              const float* __restrict__ s_a,  const float* __restrict__ tx_a,
              const float* __restrict__ ty_a,
              float* __restrict__ out) {
    __shared__ float lds[H_ * W_];               // 64 KiB

    const int plane = blockIdx.x;                // 0 .. B_*D_-1
    const float* __restrict__ img = fm + (size_t)plane * (H_ * W_);
    float* __restrict__ op = out + (size_t)plane * (H_ * W_);
    const int tid = threadIdx.x;

    // ---- stage plane -> LDS (coalesced float4, 8 iters/thread) ----
    {
        const float4* __restrict__ src = (const float4*)img;
        float4* dst = (float4*)lds;
#pragma unroll
        for (int j = 0; j < (H_ * W_ / 4) / 512; ++j) {   // 8
            dst[j * 512 + tid] = src[j * 512 + tid];
        }
    }

    const float sc = sc_a[plane];
    const float cc = c_a[plane];
    const float ss = s_a[plane];
    const float tx = tx_a[plane];
    const float ty = ty_a[plane];

    const float gstep = 2.0f / (float)(W_ - 1);
    // x = ((nx+1)*W - 1)*0.5 ; incremental step along w:
    const float dxw = cc * gstep * sc * ((float)W_ * 0.5f);
    const float dyw = ss * gstep * sc * ((float)H_ * 0.5f);

    __syncthreads();

    // ---- 4 consecutive pixels per thread per pass, float4 store ----
    // chunk of 2048 px per pass; tid*4 never crosses a 128-px row.
#pragma unroll
    for (int j = 0; j < 8; ++j) {
        const int p0 = j * 2048 + tid * 4;
        const int h = p0 >> 7;
        const int w = p0 & (W_ - 1);
        const float gx = (float)w * gstep - 1.0f;
        const float gy = (float)h * gstep - 1.0f;
        // pixel coords for w (align_corners=False):
        float xb = ((cc * gx - ss * gy) * sc + tx + 1.0f) * ((float)W_ * 0.5f) - 0.5f;
        float yb = ((ss * gx + cc * gy) * sc + ty + 1.0f) * ((float)H_ * 0.5f) - 0.5f;

        float4 res;
        float* resp = (float*)&res;
#pragma unroll
        for (int k = 0; k < 4; ++k) {
            float x = xb + (float)k * dxw;
            float y = yb + (float)k * dyw;
            x = fminf(fmaxf(x, 0.0f), (float)(W_ - 1));   // border padding
            y = fminf(fmaxf(y, 0.0f), (float)(H_ - 1));

            const float x0f = floorf(x);
            const float y0f = floorf(y);
            const float wx = x - x0f;
            const float wy = y - y0f;
            const int x0 = (int)x0f;
            const int y0 = (int)y0f;
            const int x1 = min(x0 + 1, W_ - 1);
            const int y1 = min(y0 + 1, H_ - 1);

            const float v00 = lds[y0 * W_ + x0];
            const float v01 = lds[y0 * W_ + x1];
            const float v10 = lds[y1 * W_ + x0];
            const float v11 = lds[y1 * W_ + x1];

            const float top = v00 + wx * (v01 - v00);
            const float bot = v10 + wx * (v11 - v10);
            resp[k] = top + wy * (bot - top);
        }
        *(float4*)(op + p0) = res;
    }
}

extern "C" void kernel_launch(void* const* d_in, const int* in_sizes, int n_in,
                              void* d_out, int out_size, void* d_ws, size_t ws_size,
                              hipStream_t stream) {
    const float* feature_map = (const float*)d_in[0];
    const float* para_code   = (const float*)d_in[1];
    const float* W1 = (const float*)d_in[2];
    const float* b1 = (const float*)d_in[3];
    const float* Ws = (const float*)d_in[4];
    const float* bs = (const float*)d_in[5];
    const float* Wr = (const float*)d_in[6];
    const float* br = (const float*)d_in[7];
    const float* Wt = (const float*)d_in[8];
    const float* bt = (const float*)d_in[9];
    float* out = (float*)d_out;

    // Workspace layout (floats): p[B_*PC_] | sc | c | s | tx | ty (each B_*D_)
    float* ws_f = (float*)d_ws;
    float* p_buf = ws_f;
    float* sc_a  = p_buf + B_ * PC_;
    float* c_a   = sc_a + B_ * D_;
    float* s_a   = c_a  + B_ * D_;
    float* tx_a  = s_a  + B_ * D_;
    float* ty_a  = tx_a + B_ * D_;

    k_mlp_p<<<B_, PC_, 0, stream>>>(para_code, W1, b1, p_buf);
    k_heads<<<B_, D_, 0, stream>>>(p_buf, Ws, bs, Wr, br, Wt, bt,
                                   sc_a, c_a, s_a, tx_a, ty_a);
    k_sample<<<B_ * D_, 512, 0, stream>>>(feature_map, sc_a, c_a, s_a, tx_a, ty_a, out);
}

// Round 3
// 115.176 us; speedup vs baseline: 1.7588x; 1.0153x over previous
//
#include <hip/hip_runtime.h>
#include <math.h>

// Problem shape (fixed by reference setup_inputs):
//   feature_map: (B=8, D=256, H=128, W=128) fp32
//   para_code:   (8, 256)
//   W1 (256,256) b1(256) | Ws (256,256) bs(256) | Wr (256,256) br(256)
//   Wt (256,512) bt(512)
// Output: (8, 256, 128, 128) fp32

#define B_  8
#define D_  256
#define H_  128
#define W_  128
#define PC_ 256
#define PI_F 3.14159f

// ------------- Kernel 1: fused p = relu(para@W1+b1) -> 4 heads --------------
// grid = B_, block = 256. Phase 1 computes p into LDS, phase 2 the heads.
__global__ void k_params(const float* __restrict__ para,
                         const float* __restrict__ W1, const float* __restrict__ b1,
                         const float* __restrict__ Ws, const float* __restrict__ bs,
                         const float* __restrict__ Wr, const float* __restrict__ br,
                         const float* __restrict__ Wt, const float* __restrict__ bt,
                         float* __restrict__ sc_o, float* __restrict__ c_o,
                         float* __restrict__ s_o,  float* __restrict__ tx_o,
                         float* __restrict__ ty_o) {
    __shared__ float sp[PC_];   // para row
    __shared__ float pp[PC_];   // relu'd hidden
    const int b = blockIdx.x;
    const int d = threadIdx.x;
    sp[d] = para[b * PC_ + d];
    __syncthreads();

    float acc = b1[d];
#pragma unroll 8
    for (int k = 0; k < PC_; ++k) {
        acc = fmaf(sp[k], W1[k * PC_ + d], acc);
    }
    pp[d] = fmaxf(acc, 0.0f);
    __syncthreads();

    float as = bs[d];
    float ar = br[d];
    const float2* __restrict__ Wt2 = (const float2*)Wt;  // (256, 256) of float2
    float t0 = bt[2 * d];
    float t1 = bt[2 * d + 1];
#pragma unroll 4
    for (int k = 0; k < PC_; ++k) {
        const float pk = pp[k];
        as = fmaf(pk, Ws[k * PC_ + d], as);
        ar = fmaf(pk, Wr[k * PC_ + d], ar);
        const float2 wt = Wt2[k * PC_ + d];
        t0 = fmaf(pk, wt.x, t0);
        t1 = fmaf(pk, wt.y, t1);
    }
    const int o = b * D_ + d;
    const float scale = 2.0f / (1.0f + expf(-as));      // sigmoid * 2
    const float ang   = tanhf(ar) * PI_F;
    sc_o[o] = scale;
    c_o[o]  = cosf(ang);
    s_o[o]  = sinf(ang);
    tx_o[o] = tanhf(t0);
    ty_o[o] = tanhf(t1);
}

// ------------- Kernel 2: affine grid-sample via LDS-staged plane ------------
// One 1024-thread block per (b,d) plane; 2 blocks/CU (128 KiB LDS) = 32
// waves/CU. Each lane owns ONE pixel per iteration with lanes consecutive
// in w -> gather bank = x%32 spans all 32 banks at 2 lanes/bank (free).
// (Previous version: 4 consecutive px/thread -> 8-way conflict, 40% stall.)
__global__ __launch_bounds__(1024, 8)
void k_sample(const float* __restrict__ fm,
              const float* __restrict__ sc_a, const float* __restrict__ c_a,
              const float* __restrict__ s_a,  const float* __restrict__ tx_a,
              const float* __restrict__ ty_a,
              float* __restrict__ out) {
    __shared__ float lds[H_ * W_];               // 64 KiB

    const int plane = blockIdx.x;                // 0 .. B_*D_-1
    const float* __restrict__ img = fm + (size_t)plane * (H_ * W_);
    float* __restrict__ op = out + (size_t)plane * (H_ * W_);
    const int tid = threadIdx.x;

    // ---- stage plane -> LDS (coalesced float4, 4 iters/thread) ----
    {
        const float4* __restrict__ src = (const float4*)img;
        float4* dst = (float4*)lds;
#pragma unroll
        for (int j = 0; j < 4; ++j) {
            dst[j * 1024 + tid] = src[j * 1024 + tid];
        }
    }

    const float sc = sc_a[plane];
    const float cc = c_a[plane];
    const float ss = s_a[plane];
    const float tx = tx_a[plane];
    const float ty = ty_a[plane];

    // Fold normalized->pixel mapping into x = w*ax + h*bx + cx (2 fma):
    //   gx = w*gstep-1, gy = h*gstep-1
    //   x  = ((cc*gx - ss*gy)*sc + tx + 1)*64 - 0.5
    const float gstep = 2.0f / (float)(W_ - 1);
    const float k64 = (float)W_ * 0.5f;                  // 64
    const float ax =  cc * sc * gstep * k64;
    const float bx = -ss * sc * gstep * k64;
    const float cx = (tx - cc * sc + ss * sc + 1.0f) * k64 - 0.5f;
    const float ay =  ss * sc * gstep * k64;
    const float by =  cc * sc * gstep * k64;
    const float cy = (ty - ss * sc - cc * sc + 1.0f) * k64 - 0.5f;

    __syncthreads();

    // ---- 16 px/thread: 8 iterations x 2 independent pixels (ILP) ----
#pragma unroll
    for (int j = 0; j < 8; ++j) {
#pragma unroll
        for (int k = 0; k < 2; ++k) {
            const int p0 = j * 2048 + k * 1024 + tid;
            const int h = p0 >> 7;                // W_ = 128
            const int w = p0 & (W_ - 1);
            float x = fmaf((float)w, ax, fmaf((float)h, bx, cx));
            float y = fmaf((float)w, ay, fmaf((float)h, by, cy));
            x = fminf(fmaxf(x, 0.0f), (float)(W_ - 1));   // border padding
            y = fminf(fmaxf(y, 0.0f), (float)(H_ - 1));

            const float x0f = floorf(x);
            const float y0f = floorf(y);
            const float wx = x - x0f;
            const float wy = y - y0f;
            const int x0 = (int)x0f;
            const int y0 = (int)y0f;
            const int x1 = min(x0 + 1, W_ - 1);
            const int y1 = min(y0 + 1, H_ - 1);

            const float v00 = lds[y0 * W_ + x0];
            const float v01 = lds[y0 * W_ + x1];
            const float v10 = lds[y1 * W_ + x0];
            const float v11 = lds[y1 * W_ + x1];

            const float top = v00 + wx * (v01 - v00);
            const float bot = v10 + wx * (v11 - v10);
            op[p0] = top + wy * (bot - top);
        }
    }
}

extern "C" void kernel_launch(void* const* d_in, const int* in_sizes, int n_in,
                              void* d_out, int out_size, void* d_ws, size_t ws_size,
                              hipStream_t stream) {
    const float* feature_map = (const float*)d_in[0];
    const float* para_code   = (const float*)d_in[1];
    const float* W1 = (const float*)d_in[2];
    const float* b1 = (const float*)d_in[3];
    const float* Ws = (const float*)d_in[4];
    const float* bs = (const float*)d_in[5];
    const float* Wr = (const float*)d_in[6];
    const float* br = (const float*)d_in[7];
    const float* Wt = (const float*)d_in[8];
    const float* bt = (const float*)d_in[9];
    float* out = (float*)d_out;

    // Workspace layout (floats): sc | c | s | tx | ty (each B_*D_)
    float* ws_f = (float*)d_ws;
    float* sc_a  = ws_f;
    float* c_a   = sc_a + B_ * D_;
    float* s_a   = c_a  + B_ * D_;
    float* tx_a  = s_a  + B_ * D_;
    float* ty_a  = tx_a + B_ * D_;

    k_params<<<B_, PC_, 0, stream>>>(para_code, W1, b1, Ws, bs, Wr, br, Wt, bt,
                                     sc_a, c_a, s_a, tx_a, ty_a);
    k_sample<<<B_ * D_, 1024, 0, stream>>>(feature_map, sc_a, c_a, s_a, tx_a, ty_a, out);
}

// Round 4
// 82.898 us; speedup vs baseline: 2.4437x; 1.3894x over previous
//
#include <hip/hip_runtime.h>
#include <math.h>

// Problem shape (fixed by reference setup_inputs):
//   feature_map: (B=8, D=256, H=128, W=128) fp32
//   para_code:   (8, 256)
//   W1 (256,256) b1(256) | Ws (256,256) bs(256) | Wr (256,256) br(256)
//   Wt (256,512) bt(512)
// Output: (8, 256, 128, 128) fp32

#define B_  8
#define D_  256
#define H_  128
#define W_  128
#define PC_ 256
#define PI_F 3.14159f
#define LP_ 129   // padded LDS row stride: 129 % 32 == 1 -> row-step gathers hit
                  // consecutive banks (unpadded 128 % 32 == 0 was a 32-way
                  // conflict for rotation-dominant planes = the round-3 stall)

// ------------- Kernel 1: fused p = relu(para@W1+b1) -> heads ----------------
// grid = (B_, 2): y==0 computes scale+angle (Ws,Wr), y==1 trans (Wt).
// Both recompute the cheap p vector; head phase is halved vs one block.
__global__ void k_params(const float* __restrict__ para,
                         const float* __restrict__ W1, const float* __restrict__ b1,
                         const float* __restrict__ Ws, const float* __restrict__ bs,
                         const float* __restrict__ Wr, const float* __restrict__ br,
                         const float* __restrict__ Wt, const float* __restrict__ bt,
                         float* __restrict__ sc_o, float* __restrict__ c_o,
                         float* __restrict__ s_o,  float* __restrict__ tx_o,
                         float* __restrict__ ty_o) {
    __shared__ float sp[PC_];   // para row
    __shared__ float pp[PC_];   // relu'd hidden
    const int b = blockIdx.x;
    const int which = blockIdx.y;
    const int d = threadIdx.x;
    sp[d] = para[b * PC_ + d];
    __syncthreads();

    float acc = b1[d];
#pragma unroll 8
    for (int k = 0; k < PC_; ++k) {
        acc = fmaf(sp[k], W1[k * PC_ + d], acc);
    }
    pp[d] = fmaxf(acc, 0.0f);
    __syncthreads();

    const int o = b * D_ + d;
    if (which == 0) {
        float as = bs[d];
        float ar = br[d];
#pragma unroll 8
        for (int k = 0; k < PC_; ++k) {
            const float pk = pp[k];
            as = fmaf(pk, Ws[k * PC_ + d], as);
            ar = fmaf(pk, Wr[k * PC_ + d], ar);
        }
        const float scale = 2.0f / (1.0f + expf(-as));      // sigmoid * 2
        const float ang   = tanhf(ar) * PI_F;
        sc_o[o] = scale;
        c_o[o]  = cosf(ang);
        s_o[o]  = sinf(ang);
    } else {
        const float2* __restrict__ Wt2 = (const float2*)Wt;  // (256,256) float2
        float t0 = bt[2 * d];
        float t1 = bt[2 * d + 1];
#pragma unroll 8
        for (int k = 0; k < PC_; ++k) {
            const float pk = pp[k];
            const float2 wt = Wt2[k * PC_ + d];
            t0 = fmaf(pk, wt.x, t0);
            t1 = fmaf(pk, wt.y, t1);
        }
        tx_o[o] = tanhf(t0);
        ty_o[o] = tanhf(t1);
    }
}

// ------------- Kernel 2: affine grid-sample via padded LDS plane ------------
// One 1024-thread block per (b,d) plane, 2 blocks/CU. Plane staged into LDS
// with row stride 129 (see LP_). Pad column 128 and pad row 128 are zeroed so
// the bilinear taps read x0+1 / y0+1 UNconditionally (their weights are 0 at
// the border) -> no min() clamps and the 4 taps merge into 2x ds_read2_b32.
__global__ __launch_bounds__(1024, 8)
void k_sample(const float* __restrict__ fm,
              const float* __restrict__ sc_a, const float* __restrict__ c_a,
              const float* __restrict__ s_a,  const float* __restrict__ tx_a,
              const float* __restrict__ ty_a,
              float* __restrict__ out) {
    __shared__ float lds[LP_ * LP_];             // 129 rows x 129 cols, ~65 KiB

    const int plane = blockIdx.x;                // 0 .. B_*D_-1
    const float* __restrict__ img = fm + (size_t)plane * (H_ * W_);
    float* __restrict__ op = out + (size_t)plane * (H_ * W_);
    const int tid = threadIdx.x;

    // ---- stage plane -> padded LDS (float4 global loads, scalar writes) ----
    {
        const float4* __restrict__ src = (const float4*)img;
#pragma unroll
        for (int j = 0; j < 4; ++j) {
            const float4 v = src[j * 1024 + tid];
            const int e = (j * 1024 + tid) * 4;
            const int h = e >> 7;
            const int w = e & (W_ - 1);
            float* dst = &lds[h * LP_ + w];
            dst[0] = v.x; dst[1] = v.y; dst[2] = v.z; dst[3] = v.w;
        }
        // zero the pads: column 128 of rows 0..127, and all of row 128
        if (tid < H_)       lds[tid * LP_ + W_] = 0.0f;
        if (tid < LP_)      lds[H_ * LP_ + tid] = 0.0f;
    }

    const float sc = sc_a[plane];
    const float cc = c_a[plane];
    const float ss = s_a[plane];
    const float tx = tx_a[plane];
    const float ty = ty_a[plane];

    // Fold normalized->pixel mapping into x = w*ax + h*bx + cx (2 fma):
    //   gx = w*gstep-1, gy = h*gstep-1
    //   x  = ((cc*gx - ss*gy)*sc + tx + 1)*64 - 0.5
    const float gstep = 2.0f / (float)(W_ - 1);
    const float k64 = (float)W_ * 0.5f;                  // 64
    const float ax =  cc * sc * gstep * k64;
    const float bx = -ss * sc * gstep * k64;
    const float cx = (tx - cc * sc + ss * sc + 1.0f) * k64 - 0.5f;
    const float ay =  ss * sc * gstep * k64;
    const float by =  cc * sc * gstep * k64;
    const float cy = (ty - ss * sc - cc * sc + 1.0f) * k64 - 0.5f;

    __syncthreads();

    // ---- 16 px/thread, 1 px per lane per iter (lanes consecutive in w) ----
#pragma unroll
    for (int it = 0; it < 16; ++it) {
        const int p0 = it * 1024 + tid;
        const int h = p0 >> 7;                // W_ = 128
        const int w = p0 & (W_ - 1);
        float x = fmaf((float)w, ax, fmaf((float)h, bx, cx));
        float y = fmaf((float)w, ay, fmaf((float)h, by, cy));
        x = fminf(fmaxf(x, 0.0f), (float)(W_ - 1));   // border padding
        y = fminf(fmaxf(y, 0.0f), (float)(H_ - 1));

        const float x0f = floorf(x);
        const float y0f = floorf(y);
        const float wx = x - x0f;
        const float wy = y - y0f;
        const int base = (int)y0f * LP_ + (int)x0f;

        const float v00 = lds[base];
        const float v01 = lds[base + 1];          // weight 0 if x at border
        const float v10 = lds[base + LP_];        // weight 0 if y at border
        const float v11 = lds[base + LP_ + 1];

        const float top = v00 + wx * (v01 - v00);
        const float bot = v10 + wx * (v11 - v10);
        op[p0] = top + wy * (bot - top);
    }
}

extern "C" void kernel_launch(void* const* d_in, const int* in_sizes, int n_in,
                              void* d_out, int out_size, void* d_ws, size_t ws_size,
                              hipStream_t stream) {
    const float* feature_map = (const float*)d_in[0];
    const float* para_code   = (const float*)d_in[1];
    const float* W1 = (const float*)d_in[2];
    const float* b1 = (const float*)d_in[3];
    const float* Ws = (const float*)d_in[4];
    const float* bs = (const float*)d_in[5];
    const float* Wr = (const float*)d_in[6];
    const float* br = (const float*)d_in[7];
    const float* Wt = (const float*)d_in[8];
    const float* bt = (const float*)d_in[9];
    float* out = (float*)d_out;

    // Workspace layout (floats): sc | c | s | tx | ty (each B_*D_)
    float* ws_f = (float*)d_ws;
    float* sc_a  = ws_f;
    float* c_a   = sc_a + B_ * D_;
    float* s_a   = c_a  + B_ * D_;
    float* tx_a  = s_a  + B_ * D_;
    float* ty_a  = tx_a + B_ * D_;

    k_params<<<dim3(B_, 2), PC_, 0, stream>>>(para_code, W1, b1, Ws, bs, Wr, br,
                                              Wt, bt, sc_a, c_a, s_a, tx_a, ty_a);
    k_sample<<<B_ * D_, 1024, 0, stream>>>(feature_map, sc_a, c_a, s_a, tx_a, ty_a, out);
}

// Round 5
// 82.878 us; speedup vs baseline: 2.4442x; 1.0002x over previous
//
#include <hip/hip_runtime.h>
#include <math.h>

// Problem shape (fixed by reference setup_inputs):
//   feature_map: (B=8, D=256, H=128, W=128) fp32
//   para_code:   (8, 256)
//   W1 (256,256) b1(256) | Ws (256,256) bs(256) | Wr (256,256) br(256)
//   Wt (256,512) bt(512)
// Output: (8, 256, 128, 128) fp32

#define B_  8
#define D_  256
#define H_  128
#define W_  128
#define PC_ 256
#define PI_F 3.14159f
#define LP_ 129   // padded LDS row stride: 129 % 32 == 1 -> row-step gathers hit
                  // consecutive banks (128 % 32 == 0 was a 32-way conflict for
                  // rotation-dominant planes)

// ------------- Kernel 1: fused p = relu(para@W1+b1) -> heads ----------------
__global__ void k_params(const float* __restrict__ para,
                         const float* __restrict__ W1, const float* __restrict__ b1,
                         const float* __restrict__ Ws, const float* __restrict__ bs,
                         const float* __restrict__ Wr, const float* __restrict__ br,
                         const float* __restrict__ Wt, const float* __restrict__ bt,
                         float* __restrict__ sc_o, float* __restrict__ c_o,
                         float* __restrict__ s_o,  float* __restrict__ tx_o,
                         float* __restrict__ ty_o) {
    __shared__ float sp[PC_];   // para row
    __shared__ float pp[PC_];   // relu'd hidden
    const int b = blockIdx.x;
    const int which = blockIdx.y;
    const int d = threadIdx.x;
    sp[d] = para[b * PC_ + d];
    __syncthreads();

    float acc = b1[d];
#pragma unroll 8
    for (int k = 0; k < PC_; ++k) {
        acc = fmaf(sp[k], W1[k * PC_ + d], acc);
    }
    pp[d] = fmaxf(acc, 0.0f);
    __syncthreads();

    const int o = b * D_ + d;
    if (which == 0) {
        float as = bs[d];
        float ar = br[d];
#pragma unroll 8
        for (int k = 0; k < PC_; ++k) {
            const float pk = pp[k];
            as = fmaf(pk, Ws[k * PC_ + d], as);
            ar = fmaf(pk, Wr[k * PC_ + d], ar);
        }
        const float scale = 2.0f / (1.0f + expf(-as));      // sigmoid * 2
        const float ang   = tanhf(ar) * PI_F;
        sc_o[o] = scale;
        c_o[o]  = cosf(ang);
        s_o[o]  = sinf(ang);
    } else {
        const float2* __restrict__ Wt2 = (const float2*)Wt;  // (256,256) float2
        float t0 = bt[2 * d];
        float t1 = bt[2 * d + 1];
#pragma unroll 8
        for (int k = 0; k < PC_; ++k) {
            const float pk = pp[k];
            const float2 wt = Wt2[k * PC_ + d];
            t0 = fmaf(pk, wt.x, t0);
            t1 = fmaf(pk, wt.y, t1);
        }
        tx_o[o] = tanhf(t0);
        ty_o[o] = tanhf(t1);
    }
}

// ------------- Kernel 2: affine grid-sample via padded LDS plane ------------
// One 1024-thread block per (b,d) plane, 2 blocks/CU (LDS-capped, 32 waves).
// Staging: scalar loads/writes, lane-consecutive within a row -> conflict-free
// LDS writes (the float4->4-scalar pattern was an 8-way conflict). Compute:
// 4 pixels in flight per batch (explicit ILP phases; round-4 compiler output
// had VGPR=16 = fully serialized dependent chain, LDS-latency-bound).
__global__ __launch_bounds__(1024, 8)
void k_sample(const float* __restrict__ fm,
              const float* __restrict__ sc_a, const float* __restrict__ c_a,
              const float* __restrict__ s_a,  const float* __restrict__ tx_a,
              const float* __restrict__ ty_a,
              float* __restrict__ out) {
    __shared__ float lds[LP_ * LP_];             // 129 x 129 floats, ~65 KiB

    const int plane = blockIdx.x;                // 0 .. B_*D_-1
    const float* __restrict__ img = fm + (size_t)plane * (H_ * W_);
    float* __restrict__ op = out + (size_t)plane * (H_ * W_);
    const int tid = threadIdx.x;

    // ---- stage plane -> padded LDS (scalar, conflict-free) ----
#pragma unroll
    for (int it = 0; it < 16; ++it) {
        const int idx = it * 1024 + tid;
        const int h = idx >> 7;
        const int w = idx & (W_ - 1);
        lds[h * LP_ + w] = img[idx];
    }
    // zero pads: column 128 of rows 0..127, all 129 entries of row 128
    if (tid < H_)  lds[tid * LP_ + W_] = 0.0f;
    if (tid < LP_) lds[H_ * LP_ + tid] = 0.0f;

    const float sc = sc_a[plane];
    const float cc = c_a[plane];
    const float ss = s_a[plane];
    const float tx = tx_a[plane];
    const float ty = ty_a[plane];

    // Fold normalized->pixel mapping into x = w*ax + h*bx + cx (2 fma):
    const float gstep = 2.0f / (float)(W_ - 1);
    const float k64 = (float)W_ * 0.5f;                  // 64
    const float ax =  cc * sc * gstep * k64;
    const float bx = -ss * sc * gstep * k64;
    const float cx = (tx - cc * sc + ss * sc + 1.0f) * k64 - 0.5f;
    const float ay =  ss * sc * gstep * k64;
    const float by =  cc * sc * gstep * k64;
    const float cy = (ty - ss * sc - cc * sc + 1.0f) * k64 - 0.5f;

    __syncthreads();

    // ---- 16 px/thread in 4 batches of 4 independent pixels (ILP) ----
#pragma unroll
    for (int bt4 = 0; bt4 < 4; ++bt4) {
        int   bse[4];
        float wxv[4], wyv[4];
        float v00[4], v01[4], v10[4], v11[4];

        // phase 1: addresses + issue all 16 taps (8x ds_read2_b32)
#pragma unroll
        for (int u = 0; u < 4; ++u) {
            const int p0 = (bt4 * 4 + u) * 1024 + tid;
            const int h = p0 >> 7;                // W_ = 128
            const int w = p0 & (W_ - 1);
            float x = fmaf((float)w, ax, fmaf((float)h, bx, cx));
            float y = fmaf((float)w, ay, fmaf((float)h, by, cy));
            x = fminf(fmaxf(x, 0.0f), (float)(W_ - 1));   // border padding
            y = fminf(fmaxf(y, 0.0f), (float)(H_ - 1));
            const float x0f = floorf(x);
            const float y0f = floorf(y);
            wxv[u] = x - x0f;
            wyv[u] = y - y0f;
            const int base = (int)y0f * LP_ + (int)x0f;
            bse[u] = base;
            v00[u] = lds[base];
            v01[u] = lds[base + 1];        // weight 0 when x at border
            v10[u] = lds[base + LP_];      // weight 0 when y at border
            v11[u] = lds[base + LP_ + 1];
        }
        // phase 2: lerps + coalesced scalar stores
#pragma unroll
        for (int u = 0; u < 4; ++u) {
            const int p0 = (bt4 * 4 + u) * 1024 + tid;
            const float top = v00[u] + wxv[u] * (v01[u] - v00[u]);
            const float bot = v10[u] + wxv[u] * (v11[u] - v10[u]);
            op[p0] = top + wyv[u] * (bot - top);
        }
    }
}

extern "C" void kernel_launch(void* const* d_in, const int* in_sizes, int n_in,
                              void* d_out, int out_size, void* d_ws, size_t ws_size,
                              hipStream_t stream) {
    const float* feature_map = (const float*)d_in[0];
    const float* para_code   = (const float*)d_in[1];
    const float* W1 = (const float*)d_in[2];
    const float* b1 = (const float*)d_in[3];
    const float* Ws = (const float*)d_in[4];
    const float* bs = (const float*)d_in[5];
    const float* Wr = (const float*)d_in[6];
    const float* br = (const float*)d_in[7];
    const float* Wt = (const float*)d_in[8];
    const float* bt = (const float*)d_in[9];
    float* out = (float*)d_out;

    // Workspace layout (floats): sc | c | s | tx | ty (each B_*D_)
    float* ws_f = (float*)d_ws;
    float* sc_a  = ws_f;
    float* c_a   = sc_a + B_ * D_;
    float* s_a   = c_a  + B_ * D_;
    float* tx_a  = s_a  + B_ * D_;
    float* ty_a  = tx_a + B_ * D_;

    k_params<<<dim3(B_, 2), PC_, 0, stream>>>(para_code, W1, b1, Ws, bs, Wr, br,
                                              Wt, bt, sc_a, c_a, s_a, tx_a, ty_a);
    k_sample<<<B_ * D_, 1024, 0, stream>>>(feature_map, sc_a, c_a, s_a, tx_a, ty_a, out);
}